// Round 8
// baseline (1150.680 us; speedup 1.0000x reference)
//
#include <hip/hip_runtime.h>
#include <hip/hip_fp16.h>

#define EPSV 1e-15f
#define PEPS 1e-5f

typedef float v2f __attribute__((ext_vector_type(2)));

__device__ __forceinline__ float frcp(float x) { return __builtin_amdgcn_rcpf(x); }
__device__ __forceinline__ float fexp2(float x) { return __builtin_amdgcn_exp2f(x); }
__device__ __forceinline__ float flog2(float x) { return __builtin_amdgcn_logf(x); }
__device__ __forceinline__ float projscale(float n2) {
  return n2 > (1.f - PEPS) ? (1.f - PEPS) * frcp(n2) : 1.f;
}

// ---- DPP wave64 sum ----
template <int CTRL>
__device__ __forceinline__ float dppadd(float x) {
  int y = __builtin_amdgcn_update_dpp(0, __float_as_int(x), CTRL, 0xF, 0xF, true);
  return x + __int_as_float(y);
}
__device__ __forceinline__ float wave_sum(float x) {
  x = dppadd<0x111>(x);
  x = dppadd<0x112>(x);
  x = dppadd<0x114>(x);
  x = dppadd<0x118>(x);
  x = dppadd<0x142>(x);   // row_bcast15
  x = dppadd<0x143>(x);   // row_bcast31
  return __int_as_float(__builtin_amdgcn_readlane(__float_as_int(x), 63));
}

// ---------------- Kernel A: Ux = mob_mat_mul(u, x) -> out (+EPS folded), vstats -> ws ----------------
// (unchanged from round 7)
__global__ __launch_bounds__(256) void ux_kernel(
    const float* __restrict__ x, const float* __restrict__ u,
    const float* __restrict__ bvec, float* __restrict__ out,
    float4* __restrict__ vstat, int use_vstat)
{
  __shared__ __align__(16) float xsT[256][36];

  const int tid = threadIdx.x;
  const int lane = tid & 63, wv = tid >> 6;
  const long long base = (long long)blockIdx.x * 32;

  #pragma unroll
  for (int k4 = 0; k4 < 8; ++k4) {
    float t0 = x[(base + k4 * 4 + 0) * 256 + tid];
    float t1 = x[(base + k4 * 4 + 1) * 256 + tid];
    float t2 = x[(base + k4 * 4 + 2) * 256 + tid];
    float t3 = x[(base + k4 * 4 + 3) * 256 + tid];
    float4 v; v.x = t0; v.y = t1; v.z = t2; v.w = t3;
    *reinterpret_cast<float4*>(&xsT[tid][k4 * 4]) = v;
  }
  __syncthreads();

  float4 bb = *reinterpret_cast<const float4*>(&bvec[4 * lane]);
  bb.x += EPSV; bb.y += EPSV; bb.z += EPSV; bb.w += EPSV;
  float S_vbrow = wave_sum(bb.x + bb.y + bb.z + bb.w);

  float s1[8], s2[8];
  #pragma unroll
  for (int r = 0; r < 8; ++r) { s1[r] = 0.f; s2[r] = 0.f; }
  #pragma unroll
  for (int c = 0; c < 4; ++c) {
    const int i = lane + 64 * c;
    float4 xa = *reinterpret_cast<const float4*>(&xsT[i][8 * wv]);
    float4 xb = *reinterpret_cast<const float4*>(&xsT[i][8 * wv + 4]);
    s1[0] += xa.x; s2[0] += xa.x * xa.x;
    s1[1] += xa.y; s2[1] += xa.y * xa.y;
    s1[2] += xa.z; s2[2] += xa.z * xa.z;
    s1[3] += xa.w; s2[3] += xa.w * xa.w;
    s1[4] += xb.x; s2[4] += xb.x * xb.x;
    s1[5] += xb.y; s2[5] += xb.y * xb.y;
    s1[6] += xb.z; s2[6] += xb.z * xb.z;
    s1[7] += xb.w; s2[7] += xb.w * xb.w;
  }
  float rs[8], xnr[8];
  #pragma unroll
  for (int r = 0; r < 8; ++r) {
    float a = wave_sum(s1[r]);
    float b2 = wave_sum(s2[r]);
    float sc = projscale(b2);
    rs[r] = sc;
    xnr[r] = sqrtf(sc * sc * b2 + 2.f * sc * EPSV * a + 256.f * EPSV * EPSV);
  }

  float4 acc[8];
  #pragma unroll
  for (int r = 0; r < 8; ++r) { acc[r].x = 0.f; acc[r].y = 0.f; acc[r].z = 0.f; acc[r].w = 0.f; }
  #pragma unroll 2
  for (int i = 0; i < 256; ++i) {
    float4 uv = *reinterpret_cast<const float4*>(&u[i * 256 + 4 * lane]);
    float4 xa = *reinterpret_cast<const float4*>(&xsT[i][8 * wv]);
    float4 xb = *reinterpret_cast<const float4*>(&xsT[i][8 * wv + 4]);
    acc[0].x += uv.x * xa.x; acc[0].y += uv.y * xa.x; acc[0].z += uv.z * xa.x; acc[0].w += uv.w * xa.x;
    acc[1].x += uv.x * xa.y; acc[1].y += uv.y * xa.y; acc[1].z += uv.z * xa.y; acc[1].w += uv.w * xa.y;
    acc[2].x += uv.x * xa.z; acc[2].y += uv.y * xa.z; acc[2].z += uv.z * xa.z; acc[2].w += uv.w * xa.z;
    acc[3].x += uv.x * xa.w; acc[3].y += uv.y * xa.w; acc[3].z += uv.z * xa.w; acc[3].w += uv.w * xa.w;
    acc[4].x += uv.x * xb.x; acc[4].y += uv.y * xb.x; acc[4].z += uv.z * xb.x; acc[4].w += uv.w * xb.x;
    acc[5].x += uv.x * xb.y; acc[5].y += uv.y * xb.y; acc[5].z += uv.z * xb.y; acc[5].w += uv.w * xb.y;
    acc[6].x += uv.x * xb.z; acc[6].y += uv.y * xb.z; acc[6].z += uv.z * xb.z; acc[6].w += uv.w * xb.z;
    acc[7].x += uv.x * xb.w; acc[7].y += uv.y * xb.w; acc[7].z += uv.z * xb.w; acc[7].w += uv.w * xb.w;
  }

  #pragma unroll
  for (int r = 0; r < 8; ++r) {
    float t1 = wave_sum(acc[r].x + acc[r].y + acc[r].z + acc[r].w);
    float t2 = wave_sum(acc[r].x * acc[r].x + acc[r].y * acc[r].y +
                        acc[r].z * acc[r].z + acc[r].w * acc[r].w);
    float t3 = wave_sum(acc[r].x * bb.x + acc[r].y * bb.y + acc[r].z * bb.z + acc[r].w * bb.w);
    float Sm  = rs[r] * t1;
    float Sm2 = rs[r] * rs[r] * t2;
    float mxn = sqrtf(Sm2 + 2.f * EPSV * Sm + 256.f * EPSV * EPSV);
    float xn = xnr[r];
    float at = 0.34657359f * flog2((1.f + xn) * frcp(1.f - xn));
    float arg = mxn * frcp(xn) * at;
    float e2 = fexp2(arg * 2.8853902f);
    float th = 1.f - 2.f * frcp(e2 + 1.f);
    float g = th * frcp(mxn);
    float fs = g * projscale(g * g * Sm2) * rs[r];
    float4 o;
    o.x = fs * acc[r].x + EPSV; o.y = fs * acc[r].y + EPSV;
    o.z = fs * acc[r].z + EPSV; o.w = fs * acc[r].w + EPSV;
    reinterpret_cast<float4*>(out)[(base + 8 * wv + r) * 64 + lane] = o;
    if (use_vstat && lane == 0) {
      float Sv  = fs * t1 + 256.f * EPSV;
      float Sv2 = fs * fs * t2 + 2.f * EPSV * fs * t1 + 256.f * EPSV * EPSV;
      float Svb = fs * t3 + EPSV * S_vbrow;
      vstat[base + 8 * wv + r] = float4{Sv, Sv2, Svb, 0.f};
    }
  }
}

// ---- P,Q matvec over 32 rows from fp16 W in LDS; lane owns cols 4*lane..+3 ----
__device__ __forceinline__ void mv16(const __half* __restrict__ Wl, int rbase, int lane,
                                     const float* __restrict__ mxp,
                                     const float* __restrict__ vp,
                                     float* __restrict__ Pout, float* __restrict__ Qout) {
  v2f p0{0.f,0.f}, p1{0.f,0.f}, q0{0.f,0.f}, q1{0.f,0.f};
  #pragma unroll
  for (int g = 0; g < 8; ++g) {
    float4 m4 = *reinterpret_cast<const float4*>(mxp + rbase + 4 * g);   // wave-uniform
    float4 v4 = *reinterpret_cast<const float4*>(vp + rbase + 4 * g);
    float mm[4] = {m4.x, m4.y, m4.z, m4.w};
    float vv[4] = {v4.x, v4.y, v4.z, v4.w};
    #pragma unroll
    for (int r = 0; r < 4; ++r) {
      const int i = rbase + 4 * g + r;
      const __half2* wp = reinterpret_cast<const __half2*>(Wl + (size_t)i * 256 + 4 * lane);
      float2 wa = __half22float2(wp[0]);
      float2 wb = __half22float2(wp[1]);
      v2f wa2{wa.x, wa.y}, wb2{wb.x, wb.y};
      p0 += wa2 * mm[r]; p1 += wb2 * mm[r];
      q0 += wa2 * vv[r]; q1 += wb2 * vv[r];
    }
  }
  *reinterpret_cast<float4*>(Pout + 4 * lane) = float4{p0.x, p0.y, p1.x, p1.y};
  *reinterpret_cast<float4*>(Qout + 4 * lane) = float4{q0.x, q0.y, q1.x, q1.y};
}

// ---------------- Kernel B: recurrence. W entirely in LDS as fp16 (128 KB) ----------------
// 9 waves: wave0 = serial chain; waves 1-8 = 32 K-rows each (P,Q partials);
// waves 1-4 combine 64 cols each; wave 1 stages v. 2 barriers/step.
__global__ __launch_bounds__(576) void rnn_kernel(
    const float* __restrict__ w, const float* __restrict__ bvec,
    float* __restrict__ out, const float4* __restrict__ vstat, int S, int use_vstat)
{
  __shared__ __align__(16) __half w16[256][256];   // 128 KB
  __shared__ __align__(16) float mx_lds[256];
  __shared__ __align__(16) float v_lds[2][256];
  __shared__ __align__(16) float wvb_lds[256];
  __shared__ __align__(16) float pP[8][256];
  __shared__ __align__(16) float pQ[8][256];
  __shared__ float sc_lds[4];

  const int tid = threadIdx.x;
  const int lane = tid & 63;
  const int wv = tid >> 6;                      // 0..8

  const long long rb4 = (long long)blockIdx.x * S * 64;   // float4 units
  const long long vsbase = (long long)blockIdx.x * S;
  const float4* outv = reinterpret_cast<const float4*>(out);
  float4* outw = reinterpret_cast<float4*>(out);
  const float4 zero4{0.f, 0.f, 0.f, 0.f};

  // convert W -> LDS fp16 (once): 16384 float4 groups over 576 threads
  {
    const float4* w4 = reinterpret_cast<const float4*>(w);
    __half2* W2 = reinterpret_cast<__half2*>(&w16[0][0]);
    for (int idx = tid; idx < 16384; idx += 576) {
      float4 t = w4[idx];
      W2[2 * idx]     = __floats2half2_rn(t.x, t.y);
      W2[2 * idx + 1] = __floats2half2_rn(t.z, t.w);
    }
  }

  if (wv == 0) {
    // ---- wave 0: serial chain only ----
    float4 vb4 = *reinterpret_cast<const float4*>(&bvec[4 * lane]);
    vb4.x += EPSV; vb4.y += EPSV; vb4.z += EPSV; vb4.w += EPSV;
    float S_vb  = wave_sum(vb4.x + vb4.y + vb4.z + vb4.w);
    float S_vb2 = wave_sum(vb4.x * vb4.x + vb4.y * vb4.y + vb4.z * vb4.z + vb4.w * vb4.w);

    reinterpret_cast<float4*>(mx_lds)[lane] = zero4;
    reinterpret_cast<float4*>(v_lds[0])[lane] = vb4;     // stage vb for Wvb init matvec
    __syncthreads();  // (1) w16 + staged vb + zero mx ready
    __syncthreads();  // (2) init partials ready

    float sAx = 0.f, sAy = 0.f, sAz = 0.f;
    if (use_vstat) { float4 s = vstat[vsbase]; sAx = s.x; sAy = s.y; sAz = s.z; }
    __syncthreads();  // (3) wvb_lds + real v[0] ready

    float S_h = 0.f, S_h2 = 0.f;

    for (int t = 0; t < S; ++t) {
      const int b = t & 1;
      float4 m4 = *reinterpret_cast<const float4*>(&mx_lds[4 * lane]);
      float4 v4 = *reinterpret_cast<const float4*>(&v_lds[b][4 * lane]);

      float nsx = 0.f, nsy = 0.f, nsz = 0.f;
      if (use_vstat && t + 1 < S) { float4 s = vstat[vsbase + t + 1]; nsx = s.x; nsy = s.y; nsz = s.z; }

      float S_Mx  = wave_sum(m4.x + m4.y + m4.z + m4.w);
      float S_Mx2 = wave_sum(m4.x * m4.x + m4.y * m4.y + m4.z * m4.z + m4.w * m4.w);
      float S_Mxv = wave_sum(m4.x * v4.x + m4.y * v4.y + m4.z * v4.z + m4.w * v4.w);
      float S_Mxb = wave_sum(m4.x * vb4.x + m4.y * vb4.y + m4.z * vb4.z + m4.w * vb4.w);
      float S_v, S_v2, S_vvb;
      if (use_vstat) { S_v = sAx; S_v2 = sAy; S_vvb = sAz; }
      else {
        S_v   = wave_sum(v4.x + v4.y + v4.z + v4.w);
        S_v2  = wave_sum(v4.x * v4.x + v4.y * v4.y + v4.z * v4.z + v4.w * v4.w);
        S_vvb = wave_sum(v4.x * vb4.x + v4.y * vb4.y + v4.z * vb4.z + v4.w * vb4.w);
      }

      // scalar chain (wave-uniform)
      float s_hp = projscale(S_h2);
      float xn = sqrtf(s_hp * s_hp * S_h2 + 2.f * s_hp * EPSV * S_h + 256.f * EPSV * EPSV);
      float mxn = sqrtf(S_Mx2 + 2.f * EPSV * S_Mx + 256.f * EPSV * EPSV);
      float at = 0.34657359f * flog2((1.f + xn) * frcp(1.f - xn));
      float arg = mxn * frcp(xn) * at;
      float e2 = fexp2(arg * 2.8853902f);
      float th = 1.f - 2.f * frcp(e2 + 1.f);
      float g = th * frcp(mxn);
      float beta = g * projscale(g * g * S_Mx2);

      float nuv = 2.f * beta * S_Mxv;
      float nu  = beta * beta * S_Mx2;
      float nv  = S_v2;
      float rden = frcp(1.f + nuv + nv * nu);
      float cA = (1.f + nuv + nv) * rden;
      float cB = (1.f - nu) * rden;
      float cAb = cA * beta;
      float S_r1  = cAb * S_Mx + cB * S_v;
      float S_r12 = cAb * cAb * S_Mx2 + 2.f * cAb * cB * S_Mxv + cB * cB * S_v2;
      float S_r1b = cAb * S_Mxb + cB * S_vvb;
      float s1p = projscale(S_r12);
      float S_U = s1p * S_r1, S_U2 = s1p * s1p * S_r12, S_Ub = s1p * S_r1b;

      float nuv2 = 2.f * S_Ub;
      float rden2 = frcp(1.f + nuv2 + S_vb2 * S_U2);
      float dA = (1.f + nuv2 + S_vb2) * rden2;
      float dB = (1.f - S_U2) * rden2;
      float S_hn  = dA * S_U + dB * S_vb;
      float S_hn2 = dA * dA * S_U2 + 2.f * dA * dB * S_Ub + dB * dB * S_vb2;
      float s2p = projscale(S_hn2);

      float km = s2p * dA * s1p * cAb;
      float kv = s2p * dA * s1p * cB;
      float kb = s2p * dB;

      float4 hn{km * m4.x + kv * v4.x + kb * vb4.x,
                km * m4.y + kv * v4.y + kb * vb4.y,
                km * m4.z + kv * v4.z + kb * vb4.z,
                km * m4.w + kv * v4.w + kb * vb4.w};
      outw[rb4 + (long long)t * 64 + lane] = hn;

      S_h  = s2p * S_hn;
      S_h2 = s2p * s2p * S_hn2;
      float snextp = projscale(S_h2);

      if (lane == 0) {
        sc_lds[0] = snextp * km;
        sc_lds[1] = snextp * kv;
        sc_lds[2] = snextp * kb;
      }

      __syncthreads();   // B: partials + scalars ready
      __syncthreads();   // A: mx[t+1] + staged v ready

      sAx = nsx; sAy = nsy; sAz = nsz;
    }
  } else if (wv == 1) {
    // ---- wave 1: matvec rows 0-31 + v staging + combine cols 0-63 ----
    const int rbase = 0;
    float4 vA = outv[rb4 + lane];               // v[0] (EPS folded by ux_kernel)
    float4 vB = outv[rb4 + 64 + lane];          // v[1]
    float4 vC = outv[rb4 + 128 + lane];         // v[2]
    __syncthreads();  // (1)
    mv16(&w16[0][0], rbase, lane, mx_lds, v_lds[0], pP[0], pQ[0]);
    __syncthreads();  // (2)
    {
      const int c = lane;
      float qc = 0.f;
      #pragma unroll
      for (int k = 0; k < 8; ++k) qc += pQ[k][c];
      wvb_lds[c] = qc;
      reinterpret_cast<float4*>(v_lds[0])[lane] = vA;    // real v[0]
    }
    __syncthreads();  // (3)

    for (int t = 0; t < S; ++t) {
      const int b = t & 1;
      mv16(&w16[0][0], rbase, lane, mx_lds, v_lds[b], pP[0], pQ[0]);
      if (t + 1 < S) reinterpret_cast<float4*>(v_lds[(t + 1) & 1])[lane] = vB;
      vB = vC;
      if (t + 3 < S) vC = outv[rb4 + (long long)(t + 3) * 64 + lane];
      __syncthreads();   // B
      {
        const int c = lane;
        float s0 = sc_lds[0], s1 = sc_lds[1], s2 = sc_lds[2];
        float pc = 0.f, qc = 0.f;
        #pragma unroll
        for (int k = 0; k < 8; ++k) { pc += pP[k][c]; qc += pQ[k][c]; }
        mx_lds[c] = s0 * pc + s1 * qc + s2 * wvb_lds[c];
      }
      __syncthreads();   // A
    }
  } else if (wv <= 4) {
    // ---- waves 2-4: matvec + combine ----
    const int rbase = 32 * (wv - 1);
    const int c = 64 * (wv - 1) + lane;
    __syncthreads();  // (1)
    mv16(&w16[0][0], rbase, lane, mx_lds, v_lds[0], pP[wv - 1], pQ[wv - 1]);
    __syncthreads();  // (2)
    {
      float qc = 0.f;
      #pragma unroll
      for (int k = 0; k < 8; ++k) qc += pQ[k][c];
      wvb_lds[c] = qc;
    }
    __syncthreads();  // (3)
    for (int t = 0; t < S; ++t) {
      const int b = t & 1;
      mv16(&w16[0][0], rbase, lane, mx_lds, v_lds[b], pP[wv - 1], pQ[wv - 1]);
      __syncthreads();   // B
      {
        float s0 = sc_lds[0], s1 = sc_lds[1], s2 = sc_lds[2];
        float pc = 0.f, qc = 0.f;
        #pragma unroll
        for (int k = 0; k < 8; ++k) { pc += pP[k][c]; qc += pQ[k][c]; }
        mx_lds[c] = s0 * pc + s1 * qc + s2 * wvb_lds[c];
      }
      __syncthreads();   // A
    }
  } else {
    // ---- waves 5-8: pure matvec ----
    const int rbase = 32 * (wv - 1);
    __syncthreads();  // (1)
    mv16(&w16[0][0], rbase, lane, mx_lds, v_lds[0], pP[wv - 1], pQ[wv - 1]);
    __syncthreads();  // (2)
    __syncthreads();  // (3)
    for (int t = 0; t < S; ++t) {
      const int b = t & 1;
      mv16(&w16[0][0], rbase, lane, mx_lds, v_lds[b], pP[wv - 1], pQ[wv - 1]);
      __syncthreads();   // B
      __syncthreads();   // A
    }
  }
}

extern "C" void kernel_launch(void* const* d_in, const int* in_sizes, int n_in,
                              void* d_out, int out_size, void* d_ws, size_t ws_size,
                              hipStream_t stream) {
  const float* x = (const float*)d_in[0];   // [B,S,I]
  const float* w = (const float*)d_in[1];   // [H,H]
  const float* u = (const float*)d_in[2];   // [I,H]
  const float* b = (const float*)d_in[3];   // [H]
  float* out = (float*)d_out;               // [B,S,H]

  const int nrows = in_sizes[0] / 256;      // B*S
  const int S = 512;
  const int B = nrows / S;

  const int use_vstat = (ws_size >= (size_t)nrows * 16) ? 1 : 0;
  float4* vstat = (float4*)d_ws;

  ux_kernel<<<nrows / 32, 256, 0, stream>>>(x, u, b, out, vstat, use_vstat);
  rnn_kernel<<<B, 576, 0, stream>>>(w, b, out, vstat, S, use_vstat);
}

// Round 9
// 1150.562 us; speedup vs baseline: 1.0001x; 1.0001x over previous
//
#include <hip/hip_runtime.h>
#include <hip/hip_fp16.h>

#define EPSV 1e-15f
#define PEPS 1e-5f

typedef float v2f __attribute__((ext_vector_type(2)));

__device__ __forceinline__ float frcp(float x) { return __builtin_amdgcn_rcpf(x); }
__device__ __forceinline__ float fexp2(float x) { return __builtin_amdgcn_exp2f(x); }
__device__ __forceinline__ float flog2(float x) { return __builtin_amdgcn_logf(x); }
__device__ __forceinline__ float projscale(float n2) {
  return n2 > (1.f - PEPS) ? (1.f - PEPS) * frcp(n2) : 1.f;
}

// ---- DPP wave64 sum ----
template <int CTRL>
__device__ __forceinline__ float dppadd(float x) {
  int y = __builtin_amdgcn_update_dpp(0, __float_as_int(x), CTRL, 0xF, 0xF, true);
  return x + __int_as_float(y);
}
__device__ __forceinline__ float wave_sum(float x) {
  x = dppadd<0x111>(x);
  x = dppadd<0x112>(x);
  x = dppadd<0x114>(x);
  x = dppadd<0x118>(x);
  x = dppadd<0x142>(x);   // row_bcast15
  x = dppadd<0x143>(x);   // row_bcast31
  return __int_as_float(__builtin_amdgcn_readlane(__float_as_int(x), 63));
}

// ---------------- Kernel A: Ux = mob_mat_mul(u, x) -> out (+EPS folded), vstats -> ws ----------------
// (unchanged)
__global__ __launch_bounds__(256) void ux_kernel(
    const float* __restrict__ x, const float* __restrict__ u,
    const float* __restrict__ bvec, float* __restrict__ out,
    float4* __restrict__ vstat, int use_vstat)
{
  __shared__ __align__(16) float xsT[256][36];

  const int tid = threadIdx.x;
  const int lane = tid & 63, wv = tid >> 6;
  const long long base = (long long)blockIdx.x * 32;

  #pragma unroll
  for (int k4 = 0; k4 < 8; ++k4) {
    float t0 = x[(base + k4 * 4 + 0) * 256 + tid];
    float t1 = x[(base + k4 * 4 + 1) * 256 + tid];
    float t2 = x[(base + k4 * 4 + 2) * 256 + tid];
    float t3 = x[(base + k4 * 4 + 3) * 256 + tid];
    float4 v; v.x = t0; v.y = t1; v.z = t2; v.w = t3;
    *reinterpret_cast<float4*>(&xsT[tid][k4 * 4]) = v;
  }
  __syncthreads();

  float4 bb = *reinterpret_cast<const float4*>(&bvec[4 * lane]);
  bb.x += EPSV; bb.y += EPSV; bb.z += EPSV; bb.w += EPSV;
  float S_vbrow = wave_sum(bb.x + bb.y + bb.z + bb.w);

  float s1[8], s2[8];
  #pragma unroll
  for (int r = 0; r < 8; ++r) { s1[r] = 0.f; s2[r] = 0.f; }
  #pragma unroll
  for (int c = 0; c < 4; ++c) {
    const int i = lane + 64 * c;
    float4 xa = *reinterpret_cast<const float4*>(&xsT[i][8 * wv]);
    float4 xb = *reinterpret_cast<const float4*>(&xsT[i][8 * wv + 4]);
    s1[0] += xa.x; s2[0] += xa.x * xa.x;
    s1[1] += xa.y; s2[1] += xa.y * xa.y;
    s1[2] += xa.z; s2[2] += xa.z * xa.z;
    s1[3] += xa.w; s2[3] += xa.w * xa.w;
    s1[4] += xb.x; s2[4] += xb.x * xb.x;
    s1[5] += xb.y; s2[5] += xb.y * xb.y;
    s1[6] += xb.z; s2[6] += xb.z * xb.z;
    s1[7] += xb.w; s2[7] += xb.w * xb.w;
  }
  float rs[8], xnr[8];
  #pragma unroll
  for (int r = 0; r < 8; ++r) {
    float a = wave_sum(s1[r]);
    float b2 = wave_sum(s2[r]);
    float sc = projscale(b2);
    rs[r] = sc;
    xnr[r] = sqrtf(sc * sc * b2 + 2.f * sc * EPSV * a + 256.f * EPSV * EPSV);
  }

  float4 acc[8];
  #pragma unroll
  for (int r = 0; r < 8; ++r) { acc[r].x = 0.f; acc[r].y = 0.f; acc[r].z = 0.f; acc[r].w = 0.f; }
  #pragma unroll 2
  for (int i = 0; i < 256; ++i) {
    float4 uv = *reinterpret_cast<const float4*>(&u[i * 256 + 4 * lane]);
    float4 xa = *reinterpret_cast<const float4*>(&xsT[i][8 * wv]);
    float4 xb = *reinterpret_cast<const float4*>(&xsT[i][8 * wv + 4]);
    acc[0].x += uv.x * xa.x; acc[0].y += uv.y * xa.x; acc[0].z += uv.z * xa.x; acc[0].w += uv.w * xa.x;
    acc[1].x += uv.x * xa.y; acc[1].y += uv.y * xa.y; acc[1].z += uv.z * xa.y; acc[1].w += uv.w * xa.y;
    acc[2].x += uv.x * xa.z; acc[2].y += uv.y * xa.z; acc[2].z += uv.z * xa.z; acc[2].w += uv.w * xa.z;
    acc[3].x += uv.x * xa.w; acc[3].y += uv.y * xa.w; acc[3].z += uv.z * xa.w; acc[3].w += uv.w * xa.w;
    acc[4].x += uv.x * xb.x; acc[4].y += uv.y * xb.x; acc[4].z += uv.z * xb.x; acc[4].w += uv.w * xb.x;
    acc[5].x += uv.x * xb.y; acc[5].y += uv.y * xb.y; acc[5].z += uv.z * xb.y; acc[5].w += uv.w * xb.y;
    acc[6].x += uv.x * xb.z; acc[6].y += uv.y * xb.z; acc[6].z += uv.z * xb.z; acc[6].w += uv.w * xb.z;
    acc[7].x += uv.x * xb.w; acc[7].y += uv.y * xb.w; acc[7].z += uv.z * xb.w; acc[7].w += uv.w * xb.w;
  }

  #pragma unroll
  for (int r = 0; r < 8; ++r) {
    float t1 = wave_sum(acc[r].x + acc[r].y + acc[r].z + acc[r].w);
    float t2 = wave_sum(acc[r].x * acc[r].x + acc[r].y * acc[r].y +
                        acc[r].z * acc[r].z + acc[r].w * acc[r].w);
    float t3 = wave_sum(acc[r].x * bb.x + acc[r].y * bb.y + acc[r].z * bb.z + acc[r].w * bb.w);
    float Sm  = rs[r] * t1;
    float Sm2 = rs[r] * rs[r] * t2;
    float mxn = sqrtf(Sm2 + 2.f * EPSV * Sm + 256.f * EPSV * EPSV);
    float xn = xnr[r];
    float at = 0.34657359f * flog2((1.f + xn) * frcp(1.f - xn));
    float arg = mxn * frcp(xn) * at;
    float e2 = fexp2(arg * 2.8853902f);
    float th = 1.f - 2.f * frcp(e2 + 1.f);
    float g = th * frcp(mxn);
    float fs = g * projscale(g * g * Sm2) * rs[r];
    float4 o;
    o.x = fs * acc[r].x + EPSV; o.y = fs * acc[r].y + EPSV;
    o.z = fs * acc[r].z + EPSV; o.w = fs * acc[r].w + EPSV;
    reinterpret_cast<float4*>(out)[(base + 8 * wv + r) * 64 + lane] = o;
    if (use_vstat && lane == 0) {
      float Sv  = fs * t1 + 256.f * EPSV;
      float Sv2 = fs * fs * t2 + 2.f * EPSV * fs * t1 + 256.f * EPSV * EPSV;
      float Svb = fs * t3 + EPSV * S_vbrow;
      vstat[base + 8 * wv + r] = float4{Sv, Sv2, Svb, 0.f};
    }
  }
}

// ---- P,Q matvec over 32 rows from pair-interleaved fp16 W in LDS ----
// wp[r2][c] = {W[2*r2][c], W[2*r2+1][c]}. One b128 = 4 cols x 2 rows.
// Packed accumulate: acc2[c] += wpair * {mx[r], mx[r+1]}; fold .x+.y at end.
__device__ __forceinline__ void mv_pair(const __half2 (*__restrict__ Wp)[256], int rbase, int lane,
                                        const float* __restrict__ mxp,
                                        const float* __restrict__ vp,
                                        float* __restrict__ Pout, float* __restrict__ Qout) {
  v2f pa{0.f,0.f}, pb{0.f,0.f}, pc{0.f,0.f}, pd{0.f,0.f};
  v2f qa{0.f,0.f}, qb{0.f,0.f}, qc{0.f,0.f}, qd{0.f,0.f};
  const int rb2 = rbase >> 1;
  #pragma unroll
  for (int g = 0; g < 8; ++g) {
    float4 m4 = *reinterpret_cast<const float4*>(mxp + rbase + 4 * g);  // rows 4g..4g+3 (uniform)
    float4 v4 = *reinterpret_cast<const float4*>(vp + rbase + 4 * g);
    const __half2* w0 = &Wp[rb2 + 2 * g][4 * lane];       // rows (4g, 4g+1), cols 4l..4l+3
    const __half2* w1 = &Wp[rb2 + 2 * g + 1][4 * lane];   // rows (4g+2, 4g+3)
    __half2 x0 = w0[0], x1 = w0[1], x2 = w0[2], x3 = w0[3];
    __half2 y0 = w1[0], y1 = w1[1], y2 = w1[2], y3 = w1[3];
    v2f mA{m4.x, m4.y}, mB{m4.z, m4.w};
    v2f vA{v4.x, v4.y}, vB{v4.z, v4.w};
    float2 f;
    f = __half22float2(x0); { v2f g0{f.x, f.y}; pa += g0 * mA; qa += g0 * vA; }
    f = __half22float2(x1); { v2f g1{f.x, f.y}; pb += g1 * mA; qb += g1 * vA; }
    f = __half22float2(x2); { v2f g2{f.x, f.y}; pc += g2 * mA; qc += g2 * vA; }
    f = __half22float2(x3); { v2f g3{f.x, f.y}; pd += g3 * mA; qd += g3 * vA; }
    f = __half22float2(y0); { v2f g0{f.x, f.y}; pa += g0 * mB; qa += g0 * vB; }
    f = __half22float2(y1); { v2f g1{f.x, f.y}; pb += g1 * mB; qb += g1 * vB; }
    f = __half22float2(y2); { v2f g2{f.x, f.y}; pc += g2 * mB; qc += g2 * vB; }
    f = __half22float2(y3); { v2f g3{f.x, f.y}; pd += g3 * mB; qd += g3 * vB; }
  }
  *reinterpret_cast<float4*>(Pout + 4 * lane) =
      float4{pa.x + pa.y, pb.x + pb.y, pc.x + pc.y, pd.x + pd.y};
  *reinterpret_cast<float4*>(Qout + 4 * lane) =
      float4{qa.x + qa.y, qb.x + qb.y, qc.x + qc.y, qd.x + qd.y};
}

// ---------------- Kernel B: recurrence. W in LDS as pair-interleaved fp16 (128 KB) ----------------
// 9 waves: wave0 = serial chain; waves 1-8 = 32 K-rows each (P,Q partials);
// waves 1-4 combine 64 cols each; wave 1 stages v. 2 barriers/step.
__global__ __launch_bounds__(576) void rnn_kernel(
    const float* __restrict__ w, const float* __restrict__ bvec,
    float* __restrict__ out, const float4* __restrict__ vstat, int S, int use_vstat)
{
  __shared__ __align__(16) __half2 wp[128][256];   // 128 KB, pair-interleaved
  __shared__ __align__(16) float mx_lds[256];
  __shared__ __align__(16) float v_lds[2][256];
  __shared__ __align__(16) float wvb_lds[256];
  __shared__ __align__(16) float pP[8][256];
  __shared__ __align__(16) float pQ[8][256];
  __shared__ float sc_lds[4];

  const int tid = threadIdx.x;
  const int lane = tid & 63;
  const int wv = tid >> 6;                      // 0..8

  const long long rb4 = (long long)blockIdx.x * S * 64;   // float4 units
  const long long vsbase = (long long)blockIdx.x * S;
  const float4* outv = reinterpret_cast<const float4*>(out);
  float4* outw = reinterpret_cast<float4*>(out);
  const float4 zero4{0.f, 0.f, 0.f, 0.f};

  // convert W -> LDS pair-interleaved fp16 (once)
  for (int i = tid; i < 32768; i += 576) {
    const int r2 = i >> 8, c = i & 255;
    wp[r2][c] = __floats2half2_rn(w[(2 * r2) * 256 + c], w[(2 * r2 + 1) * 256 + c]);
  }

  if (wv == 0) {
    // ---- wave 0: serial chain only ----
    float4 vb4 = *reinterpret_cast<const float4*>(&bvec[4 * lane]);
    vb4.x += EPSV; vb4.y += EPSV; vb4.z += EPSV; vb4.w += EPSV;
    float S_vb  = wave_sum(vb4.x + vb4.y + vb4.z + vb4.w);
    float S_vb2 = wave_sum(vb4.x * vb4.x + vb4.y * vb4.y + vb4.z * vb4.z + vb4.w * vb4.w);

    reinterpret_cast<float4*>(mx_lds)[lane] = zero4;
    reinterpret_cast<float4*>(v_lds[0])[lane] = vb4;     // stage vb for Wvb init matvec
    __syncthreads();  // (1) wp + staged vb + zero mx ready
    __syncthreads();  // (2) init partials ready

    float sAx = 0.f, sAy = 0.f, sAz = 0.f;
    if (use_vstat) { float4 s = vstat[vsbase]; sAx = s.x; sAy = s.y; sAz = s.z; }
    __syncthreads();  // (3) wvb_lds + real v[0] ready

    float S_h = 0.f, S_h2 = 0.f;

    for (int t = 0; t < S; ++t) {
      const int b = t & 1;
      float4 m4 = *reinterpret_cast<const float4*>(&mx_lds[4 * lane]);
      float4 v4 = *reinterpret_cast<const float4*>(&v_lds[b][4 * lane]);

      float nsx = 0.f, nsy = 0.f, nsz = 0.f;
      if (use_vstat && t + 1 < S) { float4 s = vstat[vsbase + t + 1]; nsx = s.x; nsy = s.y; nsz = s.z; }

      float S_Mx  = wave_sum(m4.x + m4.y + m4.z + m4.w);
      float S_Mx2 = wave_sum(m4.x * m4.x + m4.y * m4.y + m4.z * m4.z + m4.w * m4.w);
      float S_Mxv = wave_sum(m4.x * v4.x + m4.y * v4.y + m4.z * v4.z + m4.w * v4.w);
      float S_Mxb = wave_sum(m4.x * vb4.x + m4.y * vb4.y + m4.z * vb4.z + m4.w * vb4.w);
      float S_v, S_v2, S_vvb;
      if (use_vstat) { S_v = sAx; S_v2 = sAy; S_vvb = sAz; }
      else {
        S_v   = wave_sum(v4.x + v4.y + v4.z + v4.w);
        S_v2  = wave_sum(v4.x * v4.x + v4.y * v4.y + v4.z * v4.z + v4.w * v4.w);
        S_vvb = wave_sum(v4.x * vb4.x + v4.y * vb4.y + v4.z * vb4.z + v4.w * vb4.w);
      }

      // scalar chain (wave-uniform)
      float s_hp = projscale(S_h2);
      float xn = sqrtf(s_hp * s_hp * S_h2 + 2.f * s_hp * EPSV * S_h + 256.f * EPSV * EPSV);
      float mxn = sqrtf(S_Mx2 + 2.f * EPSV * S_Mx + 256.f * EPSV * EPSV);
      float at = 0.34657359f * flog2((1.f + xn) * frcp(1.f - xn));
      float arg = mxn * frcp(xn) * at;
      float e2 = fexp2(arg * 2.8853902f);
      float th = 1.f - 2.f * frcp(e2 + 1.f);
      float g = th * frcp(mxn);
      float beta = g * projscale(g * g * S_Mx2);

      float nuv = 2.f * beta * S_Mxv;
      float nu  = beta * beta * S_Mx2;
      float nv  = S_v2;
      float rden = frcp(1.f + nuv + nv * nu);
      float cA = (1.f + nuv + nv) * rden;
      float cB = (1.f - nu) * rden;
      float cAb = cA * beta;
      float S_r1  = cAb * S_Mx + cB * S_v;
      float S_r12 = cAb * cAb * S_Mx2 + 2.f * cAb * cB * S_Mxv + cB * cB * S_v2;
      float S_r1b = cAb * S_Mxb + cB * S_vvb;
      float s1p = projscale(S_r12);
      float S_U = s1p * S_r1, S_U2 = s1p * s1p * S_r12, S_Ub = s1p * S_r1b;

      float nuv2 = 2.f * S_Ub;
      float rden2 = frcp(1.f + nuv2 + S_vb2 * S_U2);
      float dA = (1.f + nuv2 + S_vb2) * rden2;
      float dB = (1.f - S_U2) * rden2;
      float S_hn  = dA * S_U + dB * S_vb;
      float S_hn2 = dA * dA * S_U2 + 2.f * dA * dB * S_Ub + dB * dB * S_vb2;
      float s2p = projscale(S_hn2);

      float km = s2p * dA * s1p * cAb;
      float kv = s2p * dA * s1p * cB;
      float kb = s2p * dB;

      float4 hn{km * m4.x + kv * v4.x + kb * vb4.x,
                km * m4.y + kv * v4.y + kb * vb4.y,
                km * m4.z + kv * v4.z + kb * vb4.z,
                km * m4.w + kv * v4.w + kb * vb4.w};
      outw[rb4 + (long long)t * 64 + lane] = hn;

      S_h  = s2p * S_hn;
      S_h2 = s2p * s2p * S_hn2;
      float snextp = projscale(S_h2);

      if (lane == 0) {
        sc_lds[0] = snextp * km;
        sc_lds[1] = snextp * kv;
        sc_lds[2] = snextp * kb;
      }

      __syncthreads();   // B: partials + scalars ready
      __syncthreads();   // A: mx[t+1] + staged v ready

      sAx = nsx; sAy = nsy; sAz = nsz;
    }
  } else if (wv == 1) {
    // ---- wave 1: matvec rows 0-31 + v staging + combine cols 0-63 ----
    float4 vA = outv[rb4 + lane];               // v[0] (EPS folded by ux_kernel)
    float4 vB = outv[rb4 + 64 + lane];          // v[1]
    float4 vC = outv[rb4 + 128 + lane];         // v[2]
    __syncthreads();  // (1)
    mv_pair(wp, 0, lane, mx_lds, v_lds[0], pP[0], pQ[0]);
    __syncthreads();  // (2)
    {
      const int c = lane;
      float qc = 0.f;
      #pragma unroll
      for (int k = 0; k < 8; ++k) qc += pQ[k][c];
      wvb_lds[c] = qc;
      reinterpret_cast<float4*>(v_lds[0])[lane] = vA;    // real v[0]
    }
    __syncthreads();  // (3)

    for (int t = 0; t < S; ++t) {
      const int b = t & 1;
      mv_pair(wp, 0, lane, mx_lds, v_lds[b], pP[0], pQ[0]);
      if (t + 1 < S) reinterpret_cast<float4*>(v_lds[(t + 1) & 1])[lane] = vB;
      vB = vC;
      if (t + 3 < S) vC = outv[rb4 + (long long)(t + 3) * 64 + lane];
      __syncthreads();   // B
      {
        const int c = lane;
        float s0 = sc_lds[0], s1 = sc_lds[1], s2 = sc_lds[2];
        float pc = 0.f, qc = 0.f;
        #pragma unroll
        for (int k = 0; k < 8; ++k) { pc += pP[k][c]; qc += pQ[k][c]; }
        mx_lds[c] = s0 * pc + s1 * qc + s2 * wvb_lds[c];
      }
      __syncthreads();   // A
    }
  } else if (wv <= 4) {
    // ---- waves 2-4: matvec + combine ----
    const int rbase = 32 * (wv - 1);
    const int c = 64 * (wv - 1) + lane;
    __syncthreads();  // (1)
    mv_pair(wp, rbase, lane, mx_lds, v_lds[0], pP[wv - 1], pQ[wv - 1]);
    __syncthreads();  // (2)
    {
      float qc = 0.f;
      #pragma unroll
      for (int k = 0; k < 8; ++k) qc += pQ[k][c];
      wvb_lds[c] = qc;
    }
    __syncthreads();  // (3)
    for (int t = 0; t < S; ++t) {
      const int b = t & 1;
      mv_pair(wp, rbase, lane, mx_lds, v_lds[b], pP[wv - 1], pQ[wv - 1]);
      __syncthreads();   // B
      {
        float s0 = sc_lds[0], s1 = sc_lds[1], s2 = sc_lds[2];
        float pc = 0.f, qc = 0.f;
        #pragma unroll
        for (int k = 0; k < 8; ++k) { pc += pP[k][c]; qc += pQ[k][c]; }
        mx_lds[c] = s0 * pc + s1 * qc + s2 * wvb_lds[c];
      }
      __syncthreads();   // A
    }
  } else {
    // ---- waves 5-8: pure matvec ----
    const int rbase = 32 * (wv - 1);
    __syncthreads();  // (1)
    mv_pair(wp, rbase, lane, mx_lds, v_lds[0], pP[wv - 1], pQ[wv - 1]);
    __syncthreads();  // (2)
    __syncthreads();  // (3)
    for (int t = 0; t < S; ++t) {
      const int b = t & 1;
      mv_pair(wp, rbase, lane, mx_lds, v_lds[b], pP[wv - 1], pQ[wv - 1]);
      __syncthreads();   // B
      __syncthreads();   // A
    }
  }
}

extern "C" void kernel_launch(void* const* d_in, const int* in_sizes, int n_in,
                              void* d_out, int out_size, void* d_ws, size_t ws_size,
                              hipStream_t stream) {
  const float* x = (const float*)d_in[0];   // [B,S,I]
  const float* w = (const float*)d_in[1];   // [H,H]
  const float* u = (const float*)d_in[2];   // [I,H]
  const float* b = (const float*)d_in[3];   // [H]
  float* out = (float*)d_out;               // [B,S,H]

  const int nrows = in_sizes[0] / 256;      // B*S
  const int S = 512;
  const int B = nrows / S;

  const int use_vstat = (ws_size >= (size_t)nrows * 16) ? 1 : 0;
  float4* vstat = (float4*)d_ws;

  ux_kernel<<<nrows / 32, 256, 0, stream>>>(x, u, b, out, vstat, use_vstat);
  rnn_kernel<<<B, 576, 0, stream>>>(w, b, out, vstat, S, use_vstat);
}

// Round 10
// 825.656 us; speedup vs baseline: 1.3937x; 1.3935x over previous
//
#include <hip/hip_runtime.h>
#include <hip/hip_fp16.h>

#define EPSV 1e-15f
#define PEPS 1e-5f

typedef _Float16 h2 __attribute__((ext_vector_type(2)));
typedef _Float16 h4 __attribute__((ext_vector_type(4)));

__device__ __forceinline__ float frcp(float x) { return __builtin_amdgcn_rcpf(x); }
__device__ __forceinline__ float fexp2(float x) { return __builtin_amdgcn_exp2f(x); }
__device__ __forceinline__ float flog2(float x) { return __builtin_amdgcn_logf(x); }
__device__ __forceinline__ float projscale(float n2) {
  return n2 > (1.f - PEPS) ? (1.f - PEPS) * frcp(n2) : 1.f;
}

union U32H2 { unsigned u; h2 h; };
__device__ __forceinline__ h2 u2h(unsigned u) { U32H2 t; t.u = u; return t.h; }

#if __has_builtin(__builtin_amdgcn_fdot2)
#define FDOT2(a, b, c) __builtin_amdgcn_fdot2((a), (b), (c), false)
#else
#define FDOT2(a, b, c) ((float)(a)[0] * (float)(b)[0] + ((float)(a)[1] * (float)(b)[1] + (c)))
#endif

// ---- DPP wave64 sum ----
template <int CTRL>
__device__ __forceinline__ float dppadd(float x) {
  int y = __builtin_amdgcn_update_dpp(0, __float_as_int(x), CTRL, 0xF, 0xF, true);
  return x + __int_as_float(y);
}
__device__ __forceinline__ float wave_sum(float x) {
  x = dppadd<0x111>(x);
  x = dppadd<0x112>(x);
  x = dppadd<0x114>(x);
  x = dppadd<0x118>(x);
  x = dppadd<0x142>(x);   // row_bcast15
  x = dppadd<0x143>(x);   // row_bcast31
  return __int_as_float(__builtin_amdgcn_readlane(__float_as_int(x), 63));
}

// ---------------- Kernel A: Ux = mob_mat_mul(u, x) -> out (+EPS folded), vstats -> ws ----------------
// (unchanged)
__global__ __launch_bounds__(256) void ux_kernel(
    const float* __restrict__ x, const float* __restrict__ u,
    const float* __restrict__ bvec, float* __restrict__ out,
    float4* __restrict__ vstat, int use_vstat)
{
  __shared__ __align__(16) float xsT[256][36];

  const int tid = threadIdx.x;
  const int lane = tid & 63, wv = tid >> 6;
  const long long base = (long long)blockIdx.x * 32;

  #pragma unroll
  for (int k4 = 0; k4 < 8; ++k4) {
    float t0 = x[(base + k4 * 4 + 0) * 256 + tid];
    float t1 = x[(base + k4 * 4 + 1) * 256 + tid];
    float t2 = x[(base + k4 * 4 + 2) * 256 + tid];
    float t3 = x[(base + k4 * 4 + 3) * 256 + tid];
    float4 v; v.x = t0; v.y = t1; v.z = t2; v.w = t3;
    *reinterpret_cast<float4*>(&xsT[tid][k4 * 4]) = v;
  }
  __syncthreads();

  float4 bb = *reinterpret_cast<const float4*>(&bvec[4 * lane]);
  bb.x += EPSV; bb.y += EPSV; bb.z += EPSV; bb.w += EPSV;
  float S_vbrow = wave_sum(bb.x + bb.y + bb.z + bb.w);

  float s1[8], s2[8];
  #pragma unroll
  for (int r = 0; r < 8; ++r) { s1[r] = 0.f; s2[r] = 0.f; }
  #pragma unroll
  for (int c = 0; c < 4; ++c) {
    const int i = lane + 64 * c;
    float4 xa = *reinterpret_cast<const float4*>(&xsT[i][8 * wv]);
    float4 xb = *reinterpret_cast<const float4*>(&xsT[i][8 * wv + 4]);
    s1[0] += xa.x; s2[0] += xa.x * xa.x;
    s1[1] += xa.y; s2[1] += xa.y * xa.y;
    s1[2] += xa.z; s2[2] += xa.z * xa.z;
    s1[3] += xa.w; s2[3] += xa.w * xa.w;
    s1[4] += xb.x; s2[4] += xb.x * xb.x;
    s1[5] += xb.y; s2[5] += xb.y * xb.y;
    s1[6] += xb.z; s2[6] += xb.z * xb.z;
    s1[7] += xb.w; s2[7] += xb.w * xb.w;
  }
  float rs[8], xnr[8];
  #pragma unroll
  for (int r = 0; r < 8; ++r) {
    float a = wave_sum(s1[r]);
    float b2 = wave_sum(s2[r]);
    float sc = projscale(b2);
    rs[r] = sc;
    xnr[r] = sqrtf(sc * sc * b2 + 2.f * sc * EPSV * a + 256.f * EPSV * EPSV);
  }

  float4 acc[8];
  #pragma unroll
  for (int r = 0; r < 8; ++r) { acc[r].x = 0.f; acc[r].y = 0.f; acc[r].z = 0.f; acc[r].w = 0.f; }
  #pragma unroll 2
  for (int i = 0; i < 256; ++i) {
    float4 uv = *reinterpret_cast<const float4*>(&u[i * 256 + 4 * lane]);
    float4 xa = *reinterpret_cast<const float4*>(&xsT[i][8 * wv]);
    float4 xb = *reinterpret_cast<const float4*>(&xsT[i][8 * wv + 4]);
    acc[0].x += uv.x * xa.x; acc[0].y += uv.y * xa.x; acc[0].z += uv.z * xa.x; acc[0].w += uv.w * xa.x;
    acc[1].x += uv.x * xa.y; acc[1].y += uv.y * xa.y; acc[1].z += uv.z * xa.y; acc[1].w += uv.w * xa.y;
    acc[2].x += uv.x * xa.z; acc[2].y += uv.y * xa.z; acc[2].z += uv.z * xa.z; acc[2].w += uv.w * xa.z;
    acc[3].x += uv.x * xa.w; acc[3].y += uv.y * xa.w; acc[3].z += uv.z * xa.w; acc[3].w += uv.w * xa.w;
    acc[4].x += uv.x * xb.x; acc[4].y += uv.y * xb.x; acc[4].z += uv.z * xb.x; acc[4].w += uv.w * xb.x;
    acc[5].x += uv.x * xb.y; acc[5].y += uv.y * xb.y; acc[5].z += uv.z * xb.y; acc[5].w += uv.w * xb.y;
    acc[6].x += uv.x * xb.z; acc[6].y += uv.y * xb.z; acc[6].z += uv.z * xb.z; acc[6].w += uv.w * xb.z;
    acc[7].x += uv.x * xb.w; acc[7].y += uv.y * xb.w; acc[7].z += uv.z * xb.w; acc[7].w += uv.w * xb.w;
  }

  #pragma unroll
  for (int r = 0; r < 8; ++r) {
    float t1 = wave_sum(acc[r].x + acc[r].y + acc[r].z + acc[r].w);
    float t2 = wave_sum(acc[r].x * acc[r].x + acc[r].y * acc[r].y +
                        acc[r].z * acc[r].z + acc[r].w * acc[r].w);
    float t3 = wave_sum(acc[r].x * bb.x + acc[r].y * bb.y + acc[r].z * bb.z + acc[r].w * bb.w);
    float Sm  = rs[r] * t1;
    float Sm2 = rs[r] * rs[r] * t2;
    float mxn = sqrtf(Sm2 + 2.f * EPSV * Sm + 256.f * EPSV * EPSV);
    float xn = xnr[r];
    float at = 0.34657359f * flog2((1.f + xn) * frcp(1.f - xn));
    float arg = mxn * frcp(xn) * at;
    float e2 = fexp2(arg * 2.8853902f);
    float th = 1.f - 2.f * frcp(e2 + 1.f);
    float g = th * frcp(mxn);
    float fs = g * projscale(g * g * Sm2) * rs[r];
    float4 o;
    o.x = fs * acc[r].x + EPSV; o.y = fs * acc[r].y + EPSV;
    o.z = fs * acc[r].z + EPSV; o.w = fs * acc[r].w + EPSV;
    reinterpret_cast<float4*>(out)[(base + 8 * wv + r) * 64 + lane] = o;
    if (use_vstat && lane == 0) {
      float Sv  = fs * t1 + 256.f * EPSV;
      float Sv2 = fs * fs * t2 + 2.f * EPSV * fs * t1 + 256.f * EPSV * EPSV;
      float Svb = fs * t3 + EPSV * S_vbrow;
      vstat[base + 8 * wv + r] = float4{Sv, Sv2, Svb, 0.f};
    }
  }
}

// ---- P,Q matvec over 32 rows via v_dot2_f32_f16; lane owns cols 4l..4l+3 ----
// wph[p][c] = {W[2p][c], W[2p+1][c]}; mxh[p] = {mx[2p], mx[2p+1]}; vh likewise.
__device__ __forceinline__ void mv_dot2(const h2 (*__restrict__ Wp)[256], int r2b, int lane,
                                        const h2* __restrict__ mxh, const h2* __restrict__ vhb,
                                        float* __restrict__ Pout, float* __restrict__ Qout) {
  float p0 = 0.f, p1 = 0.f, p2 = 0.f, p3 = 0.f;
  float q0 = 0.f, q1 = 0.f, q2 = 0.f, q3 = 0.f;
  #pragma unroll
  for (int g = 0; g < 4; ++g) {
    uint4 mr = *reinterpret_cast<const uint4*>(mxh + r2b + 4 * g);   // 4 row-pairs (uniform)
    uint4 vr = *reinterpret_cast<const uint4*>(vhb + r2b + 4 * g);
    unsigned mm[4] = {mr.x, mr.y, mr.z, mr.w};
    unsigned vv[4] = {vr.x, vr.y, vr.z, vr.w};
    #pragma unroll
    for (int j = 0; j < 4; ++j) {
      uint4 wr = *reinterpret_cast<const uint4*>(&Wp[r2b + 4 * g + j][4 * lane]);
      h2 m = u2h(mm[j]), v = u2h(vv[j]);
      p0 = FDOT2(u2h(wr.x), m, p0); q0 = FDOT2(u2h(wr.x), v, q0);
      p1 = FDOT2(u2h(wr.y), m, p1); q1 = FDOT2(u2h(wr.y), v, q1);
      p2 = FDOT2(u2h(wr.z), m, p2); q2 = FDOT2(u2h(wr.z), v, q2);
      p3 = FDOT2(u2h(wr.w), m, p3); q3 = FDOT2(u2h(wr.w), v, q3);
    }
  }
  *reinterpret_cast<float4*>(Pout + 4 * lane) = float4{p0, p1, p2, p3};
  *reinterpret_cast<float4*>(Qout + 4 * lane) = float4{q0, q1, q2, q3};
}

// ---------------- Kernel B: recurrence. W fp16 in LDS, matvec via v_dot2_f32_f16 ----------------
// 9 waves: wave0 = chain; waves 1-8 = 32 rows each; wave1 stages v (fp32+fp16);
// waves 2-3 combine (2 adjacent cols/lane -> fp32 mx + packed fp16 mxh). 2 barriers/step.
__global__ __launch_bounds__(576) void rnn_kernel(
    const float* __restrict__ w, const float* __restrict__ bvec,
    float* __restrict__ out, const float4* __restrict__ vstat, int S, int use_vstat)
{
  __shared__ __align__(16) h2 wph[128][256];       // 128 KB pair-interleaved fp16 W
  __shared__ __align__(16) float mx_lds[256];
  __shared__ __align__(16) h2 mxh[128];            // fp16 mirror of mx
  __shared__ __align__(16) float v_lds[2][256];
  __shared__ __align__(16) h2 vh[2][128];          // fp16 mirror of v
  __shared__ __align__(16) float wvb_lds[256];
  __shared__ __align__(16) float pP[8][256];
  __shared__ __align__(16) float pQ[8][256];
  __shared__ float sc_lds[4];

  const int tid = threadIdx.x;
  const int lane = tid & 63;
  const int wv = tid >> 6;                      // 0..8

  const long long rb4 = (long long)blockIdx.x * S * 64;   // float4 units
  const long long vsbase = (long long)blockIdx.x * S;
  const float4* outv = reinterpret_cast<const float4*>(out);
  float4* outw = reinterpret_cast<float4*>(out);
  const float4 zero4{0.f, 0.f, 0.f, 0.f};

  // convert W -> LDS pair-interleaved fp16 (once, RNE)
  for (int i = tid; i < 32768; i += 576) {
    const int p = i >> 8, c = i & 255;
    wph[p][c] = h2{(_Float16)w[(2 * p) * 256 + c], (_Float16)w[(2 * p + 1) * 256 + c]};
  }

  if (wv == 0) {
    // ---- wave 0: serial chain ----
    float4 vb4 = *reinterpret_cast<const float4*>(&bvec[4 * lane]);
    vb4.x += EPSV; vb4.y += EPSV; vb4.z += EPSV; vb4.w += EPSV;
    float S_vb  = wave_sum(vb4.x + vb4.y + vb4.z + vb4.w);
    float S_vb2 = wave_sum(vb4.x * vb4.x + vb4.y * vb4.y + vb4.z * vb4.z + vb4.w * vb4.w);

    reinterpret_cast<float4*>(mx_lds)[lane] = zero4;
    *reinterpret_cast<h4*>(&mxh[2 * lane]) = h4{(_Float16)0.f, (_Float16)0.f, (_Float16)0.f, (_Float16)0.f};
    reinterpret_cast<float4*>(v_lds[0])[lane] = vb4;     // stage vb for Wvb init matvec
    *reinterpret_cast<h4*>(&vh[0][2 * lane]) =
        h4{(_Float16)vb4.x, (_Float16)vb4.y, (_Float16)vb4.z, (_Float16)vb4.w};
    __syncthreads();  // (1) wph + staged vb/mx (fp32+fp16) ready
    __syncthreads();  // (2) init partials ready

    float sAx = 0.f, sAy = 0.f, sAz = 0.f;
    if (use_vstat) { float4 s = vstat[vsbase]; sAx = s.x; sAy = s.y; sAz = s.z; }
    __syncthreads();  // (3) wvb_lds + real v[0] ready

    float S_h = 0.f, S_h2 = 0.f;

    for (int t = 0; t < S; ++t) {
      const int b = t & 1;
      float4 m4 = *reinterpret_cast<const float4*>(&mx_lds[4 * lane]);
      float4 v4 = *reinterpret_cast<const float4*>(&v_lds[b][4 * lane]);

      float nsx = 0.f, nsy = 0.f, nsz = 0.f;
      if (use_vstat && t + 1 < S) { float4 s = vstat[vsbase + t + 1]; nsx = s.x; nsy = s.y; nsz = s.z; }

      float S_Mx  = wave_sum(m4.x + m4.y + m4.z + m4.w);
      float S_Mx2 = wave_sum(m4.x * m4.x + m4.y * m4.y + m4.z * m4.z + m4.w * m4.w);
      float S_Mxv = wave_sum(m4.x * v4.x + m4.y * v4.y + m4.z * v4.z + m4.w * v4.w);
      float S_Mxb = wave_sum(m4.x * vb4.x + m4.y * vb4.y + m4.z * vb4.z + m4.w * vb4.w);
      float S_v, S_v2, S_vvb;
      if (use_vstat) { S_v = sAx; S_v2 = sAy; S_vvb = sAz; }
      else {
        S_v   = wave_sum(v4.x + v4.y + v4.z + v4.w);
        S_v2  = wave_sum(v4.x * v4.x + v4.y * v4.y + v4.z * v4.z + v4.w * v4.w);
        S_vvb = wave_sum(v4.x * vb4.x + v4.y * vb4.y + v4.z * vb4.z + v4.w * vb4.w);
      }

      // scalar chain (wave-uniform)
      float s_hp = projscale(S_h2);
      float xn = sqrtf(s_hp * s_hp * S_h2 + 2.f * s_hp * EPSV * S_h + 256.f * EPSV * EPSV);
      float mxn = sqrtf(S_Mx2 + 2.f * EPSV * S_Mx + 256.f * EPSV * EPSV);
      float at = 0.34657359f * flog2((1.f + xn) * frcp(1.f - xn));
      float arg = mxn * frcp(xn) * at;
      float e2 = fexp2(arg * 2.8853902f);
      float th = 1.f - 2.f * frcp(e2 + 1.f);
      float g = th * frcp(mxn);
      float beta = g * projscale(g * g * S_Mx2);

      float nuv = 2.f * beta * S_Mxv;
      float nu  = beta * beta * S_Mx2;
      float nv  = S_v2;
      float rden = frcp(1.f + nuv + nv * nu);
      float cA = (1.f + nuv + nv) * rden;
      float cB = (1.f - nu) * rden;
      float cAb = cA * beta;
      float S_r1  = cAb * S_Mx + cB * S_v;
      float S_r12 = cAb * cAb * S_Mx2 + 2.f * cAb * cB * S_Mxv + cB * cB * S_v2;
      float S_r1b = cAb * S_Mxb + cB * S_vvb;
      float s1p = projscale(S_r12);
      float S_U = s1p * S_r1, S_U2 = s1p * s1p * S_r12, S_Ub = s1p * S_r1b;

      float nuv2 = 2.f * S_Ub;
      float rden2 = frcp(1.f + nuv2 + S_vb2 * S_U2);
      float dA = (1.f + nuv2 + S_vb2) * rden2;
      float dB = (1.f - S_U2) * rden2;
      float S_hn  = dA * S_U + dB * S_vb;
      float S_hn2 = dA * dA * S_U2 + 2.f * dA * dB * S_Ub + dB * dB * S_vb2;
      float s2p = projscale(S_hn2);

      float km = s2p * dA * s1p * cAb;
      float kv = s2p * dA * s1p * cB;
      float kb = s2p * dB;

      float4 hn{km * m4.x + kv * v4.x + kb * vb4.x,
                km * m4.y + kv * v4.y + kb * vb4.y,
                km * m4.z + kv * v4.z + kb * vb4.z,
                km * m4.w + kv * v4.w + kb * vb4.w};
      outw[rb4 + (long long)t * 64 + lane] = hn;

      S_h  = s2p * S_hn;
      S_h2 = s2p * s2p * S_hn2;
      float snextp = projscale(S_h2);

      if (lane == 0) {
        sc_lds[0] = snextp * km;
        sc_lds[1] = snextp * kv;
        sc_lds[2] = snextp * kb;
      }

      __syncthreads();   // B: partials + scalars ready
      __syncthreads();   // A: mx[t+1] (fp32+fp16) + staged v ready

      sAx = nsx; sAy = nsy; sAz = nsz;
    }
  } else if (wv == 1) {
    // ---- wave 1: matvec rows 0-31 + v staging (fp32 + fp16) ----
    float4 vA = outv[rb4 + lane];               // v[0] (EPS folded by ux_kernel)
    float4 vB = outv[rb4 + 64 + lane];          // v[1]
    float4 vC = outv[rb4 + 128 + lane];         // v[2]
    __syncthreads();  // (1)
    mv_dot2(wph, 0, lane, mxh, vh[0], pP[0], pQ[0]);
    __syncthreads();  // (2)
    reinterpret_cast<float4*>(v_lds[0])[lane] = vA;      // real v[0]
    *reinterpret_cast<h4*>(&vh[0][2 * lane]) =
        h4{(_Float16)vA.x, (_Float16)vA.y, (_Float16)vA.z, (_Float16)vA.w};
    __syncthreads();  // (3)

    for (int t = 0; t < S; ++t) {
      const int b = t & 1;
      mv_dot2(wph, 0, lane, mxh, vh[b], pP[0], pQ[0]);
      if (t + 1 < S) {
        reinterpret_cast<float4*>(v_lds[(t + 1) & 1])[lane] = vB;
        *reinterpret_cast<h4*>(&vh[(t + 1) & 1][2 * lane]) =
            h4{(_Float16)vB.x, (_Float16)vB.y, (_Float16)vB.z, (_Float16)vB.w};
      }
      vB = vC;
      if (t + 3 < S) vC = outv[rb4 + (long long)(t + 3) * 64 + lane];
      __syncthreads();   // B
      __syncthreads();   // A
    }
  } else if (wv <= 3) {
    // ---- waves 2-3: matvec + combine (pair of adjacent cols per lane) ----
    const int rbase = 32 * (wv - 1);
    const int p = 64 * (wv - 2) + lane;          // pair index; cols 2p, 2p+1
    const int c0 = 2 * p;
    __syncthreads();  // (1)
    mv_dot2(wph, rbase >> 1, lane, mxh, vh[0], pP[wv - 1], pQ[wv - 1]);
    __syncthreads();  // (2)
    {
      float qa = 0.f, qb = 0.f;
      #pragma unroll
      for (int k = 0; k < 8; ++k) {
        float2 qq = *reinterpret_cast<const float2*>(&pQ[k][c0]);
        qa += qq.x; qb += qq.y;
      }
      *reinterpret_cast<float2*>(&wvb_lds[c0]) = float2{qa, qb};
    }
    __syncthreads();  // (3)
    for (int t = 0; t < S; ++t) {
      const int b = t & 1;
      mv_dot2(wph, rbase >> 1, lane, mxh, vh[b], pP[wv - 1], pQ[wv - 1]);
      __syncthreads();   // B
      {
        float s0 = sc_lds[0], s1 = sc_lds[1], s2 = sc_lds[2];
        float pa = 0.f, pb = 0.f, qa = 0.f, qb = 0.f;
        #pragma unroll
        for (int k = 0; k < 8; ++k) {
          float2 pp = *reinterpret_cast<const float2*>(&pP[k][c0]);
          float2 qq = *reinterpret_cast<const float2*>(&pQ[k][c0]);
          pa += pp.x; pb += pp.y; qa += qq.x; qb += qq.y;
        }
        float2 wb = *reinterpret_cast<const float2*>(&wvb_lds[c0]);
        float m0 = s0 * pa + s1 * qa + s2 * wb.x;
        float m1 = s0 * pb + s1 * qb + s2 * wb.y;
        *reinterpret_cast<float2*>(&mx_lds[c0]) = float2{m0, m1};
        mxh[p] = h2{(_Float16)m0, (_Float16)m1};
      }
      __syncthreads();   // A
    }
  } else {
    // ---- waves 4-8: pure matvec ----
    const int r2b = 16 * (wv - 1);
    __syncthreads();  // (1)
    mv_dot2(wph, r2b, lane, mxh, vh[0], pP[wv - 1], pQ[wv - 1]);
    __syncthreads();  // (2)
    __syncthreads();  // (3)
    for (int t = 0; t < S; ++t) {
      const int b = t & 1;
      mv_dot2(wph, r2b, lane, mxh, vh[b], pP[wv - 1], pQ[wv - 1]);
      __syncthreads();   // B
      __syncthreads();   // A
    }
  }
}

extern "C" void kernel_launch(void* const* d_in, const int* in_sizes, int n_in,
                              void* d_out, int out_size, void* d_ws, size_t ws_size,
                              hipStream_t stream) {
  const float* x = (const float*)d_in[0];   // [B,S,I]
  const float* w = (const float*)d_in[1];   // [H,H]
  const float* u = (const float*)d_in[2];   // [I,H]
  const float* b = (const float*)d_in[3];   // [H]
  float* out = (float*)d_out;               // [B,S,H]

  const int nrows = in_sizes[0] / 256;      // B*S
  const int S = 512;
  const int B = nrows / S;

  const int use_vstat = (ws_size >= (size_t)nrows * 16) ? 1 : 0;
  float4* vstat = (float4*)d_ws;

  ux_kernel<<<nrows / 32, 256, 0, stream>>>(x, u, b, out, vstat, use_vstat);
  rnn_kernel<<<B, 576, 0, stream>>>(w, b, out, vstat, S, use_vstat);
}